// Round 2
// baseline (26.123 us; speedup 1.0000x reference)
//
#include <hip/hip_runtime.h>

// DIM=2, L=13 (n = 8192 rows), BATCH=2048 cols, Hadamard on wires {0,5,9}
// -> row-index bits {12,7,3}. Real Hadamard matrix => real/imag decouple;
// harness output is the real part (out_size == n*b float32).
// 3-stage +- butterfly over row bits {3,7,12}, scale (1/sqrt(2))^3.

#define NROWS   8192
#define NCOLS   2048
#define COLS4   (NCOLS / 4)          // 512 float4 per row
#define NBASE   (NROWS / 8)          // 1024 base rows (bits 12,7,3 clear)
#define SCALE   0.35355339059327373f

// float4-unit strides for the three butterfly bits
#define D3   (8    * COLS4)   // bit 3  -> +8 rows
#define D7   (128  * COLS4)   // bit 7  -> +128 rows
#define D12  (4096 * COLS4)   // bit 12 -> +4096 rows

typedef float f32x4 __attribute__((ext_vector_type(4)));

__global__ __launch_bounds__(256) void had3_kernel(const f32x4* __restrict__ in,
                                                   f32x4* __restrict__ out) {
    int t = blockIdx.x * blockDim.x + threadIdx.x;   // 0 .. NBASE*COLS4-1
    int c    = t & (COLS4 - 1);                      // float4 column index
    int base = t >> 9;                               // 0 .. 1023

    // Expand 10 free bits of `base` into row bits {0-2, 4-6, 8-11}
    int r0 = (base & 0x7) | ((base & 0x38) << 1) | ((base & 0x3C0) << 2);
    int idx = r0 * COLS4 + c;                        // max 4M float4 -> fits int

    f32x4 v0 = __builtin_nontemporal_load(in + idx);
    f32x4 v1 = __builtin_nontemporal_load(in + idx + D3);
    f32x4 v2 = __builtin_nontemporal_load(in + idx + D7);
    f32x4 v3 = __builtin_nontemporal_load(in + idx + D7 + D3);
    f32x4 v4 = __builtin_nontemporal_load(in + idx + D12);
    f32x4 v5 = __builtin_nontemporal_load(in + idx + D12 + D3);
    f32x4 v6 = __builtin_nontemporal_load(in + idx + D12 + D7);
    f32x4 v7 = __builtin_nontemporal_load(in + idx + D12 + D7 + D3);

    // stage 1: bit 3
    f32x4 t0 = v0 + v1, t1 = v0 - v1;
    f32x4 t2 = v2 + v3, t3 = v2 - v3;
    f32x4 t4 = v4 + v5, t5 = v4 - v5;
    f32x4 t6 = v6 + v7, t7 = v6 - v7;
    // stage 2: bit 7
    f32x4 u0 = t0 + t2, u2 = t0 - t2;
    f32x4 u1 = t1 + t3, u3 = t1 - t3;
    f32x4 u4 = t4 + t6, u6 = t4 - t6;
    f32x4 u5 = t5 + t7, u7 = t5 - t7;
    // stage 3: bit 12 + scale
    f32x4 s = {SCALE, SCALE, SCALE, SCALE};
    __builtin_nontemporal_store((u0 + u4) * s, out + idx);
    __builtin_nontemporal_store((u1 + u5) * s, out + idx + D3);
    __builtin_nontemporal_store((u2 + u6) * s, out + idx + D7);
    __builtin_nontemporal_store((u3 + u7) * s, out + idx + D7 + D3);
    __builtin_nontemporal_store((u0 - u4) * s, out + idx + D12);
    __builtin_nontemporal_store((u1 - u5) * s, out + idx + D12 + D3);
    __builtin_nontemporal_store((u2 - u6) * s, out + idx + D12 + D7);
    __builtin_nontemporal_store((u3 - u7) * s, out + idx + D12 + D7 + D3);
}

extern "C" void kernel_launch(void* const* d_in, const int* in_sizes, int n_in,
                              void* d_out, int out_size, void* d_ws, size_t ws_size,
                              hipStream_t stream) {
    const float* xr = (const float*)d_in[0];
    const float* xi = (const float*)d_in[1];
    float* out = (float*)d_out;

    const int N = NROWS * NCOLS;               // 16,777,216 elements per part
    const int threads = 256;
    const int total   = NBASE * COLS4;         // 524,288 threads
    const int blocks  = total / threads;       // 2048

    had3_kernel<<<blocks, threads, 0, stream>>>((const f32x4*)xr, (f32x4*)out);

    // Defensive: if the harness wants both parts (concatenated flat),
    // transform the imaginary part into the second half.
    if (out_size >= 2 * N) {
        had3_kernel<<<blocks, threads, 0, stream>>>((const f32x4*)xi,
                                                    (f32x4*)(out + N));
    }
}